// Round 4
// baseline (713.236 us; speedup 1.0000x reference)
//
#include <hip/hip_runtime.h>
#include <math.h>

#define NNODE 10000
#define NEDGE 160000
#define BATCH 64
#define KDIM  512   // inner dim of the two big GEMMs

// ---- bf16 helpers (RNE) ----
__device__ __forceinline__ unsigned short f2bf(float x) {
  union { float f; unsigned u; } v; v.f = x;
  return (unsigned short)((v.u + 0x7FFF + ((v.u >> 16) & 1)) >> 16);
}
__device__ __forceinline__ float bf2f(unsigned short h) {
  union { unsigned u; float f; } v; v.u = ((unsigned)h) << 16;
  return v.f;
}

// ---------------- graph build ----------------

__global__ void k_init_counts(int* counts) {
  int i = blockIdx.x * 256 + threadIdx.x;
  if (i < NNODE) counts[i] = 1;   // self-loop
}

__global__ void k_count(const int* __restrict__ ei, int* counts) {
  int e = blockIdx.x * 256 + threadIdx.x;
  if (e < NEDGE) atomicAdd(&counts[ei[NEDGE + e]], 1);  // dst row
}

__global__ __launch_bounds__(1024) void k_scan(const int* __restrict__ counts,
                                               int* offs, int* cursor, float* dinv) {
  __shared__ int sd[1024];
  int t = threadIdx.x;
  int b0 = t * 10, b1 = b0 + 10;
  if (b1 > NNODE) b1 = NNODE;
  if (b0 > NNODE) b0 = NNODE;
  int s = 0;
  for (int i = b0; i < b1; i++) s += counts[i];
  sd[t] = s;
  __syncthreads();
  for (int off = 1; off < 1024; off <<= 1) {
    int v = (t >= off) ? sd[t - off] : 0;
    __syncthreads();
    sd[t] += v;
    __syncthreads();
  }
  int excl = (t == 0) ? 0 : sd[t - 1];
  for (int i = b0; i < b1; i++) {
    offs[i] = excl;
    cursor[i] = excl;
    dinv[i] = rsqrtf((float)counts[i]);
    excl += counts[i];
  }
  if (t == 1023) offs[NNODE] = sd[1023];
}

__global__ void k_fill(const int* __restrict__ ei, const float* __restrict__ dinv,
                       int* cursor, int* srcn, float* wnorm) {
  int e = blockIdx.x * 256 + threadIdx.x;
  if (e >= NEDGE + NNODE) return;
  int s, d;
  if (e < NEDGE) { s = ei[e]; d = ei[NEDGE + e]; }
  else           { s = e - NEDGE; d = s; }
  int pos = atomicAdd(&cursor[d], 1);
  srcn[pos] = s;
  wnorm[pos] = dinv[s] * dinv[d];
}

// ---------------- mlp2: net1 = tanh(net @ W_mlp2), [64,640]@[640,1024] ----------------
// 256 blocks = 64 batches x 4 col-groups of 256; thread owns one output col.

__global__ __launch_bounds__(256) void k_mlp2(const float* __restrict__ net,
                                              const float* __restrict__ W,
                                              float* __restrict__ net1) {
  __shared__ float a[640];
  int bb = blockIdx.x >> 2, cg = (blockIdx.x & 3) << 8;
  int t = threadIdx.x;
  for (int i = t; i < 640; i += 256) a[i] = net[bb * 640 + i];
  __syncthreads();
  float acc = 0.f;
#pragma unroll 4
  for (int k = 0; k < 640; k++) acc += a[k] * W[k * 1024 + cg + t];
  net1[bb * 1024 + cg + t] = tanhf(acc);
}

// ------------- fused big GEMM + tanh + per-node CxC transform -------------
// H_trans[(n*64+b)*C + d] = sum_c tanh(sum_k A[b,k] W[k,n*C+c]) * W1[c,d]   (bf16 out)
// Tile 64 rows x 48 cols (48 = exact divisor of 30000/60000). 192 thr =
// 12 col-thr (4 cols, float4 W loads) x 16 row-thr (4 rows, r = tr+16i).
// Per 4k-step: 4 ds_read_b128 + 4 float4 W loads -> 64 FMA.

template <int C>
__device__ __forceinline__ void gemm_body(const float* __restrict__ A,
                                          const float* __restrict__ W,
                                          const float* __restrict__ W1,
                                          float* lds, float* w1sh,
                                          unsigned short* __restrict__ Hout,
                                          int NC, int blk) {
  constexpr int NODE_F = 64 * C;        // elems per node chunk
  constexpr int NODE_P = NODE_F + 4;    // padded LDS stride
  int tid = threadIdx.x;
  if (tid < C * C) w1sh[tid] = W1[tid];
  int tc = tid % 12, tr = tid / 12;
  int c0 = blk * 48;

  float acc[4][4];
#pragma unroll
  for (int i = 0; i < 4; i++)
#pragma unroll
    for (int j = 0; j < 4; j++) acc[i][j] = 0.f;

  for (int kc = 0; kc < KDIM; kc += 64) {
    __syncthreads();
    for (int idx = tid; idx < 64 * 64; idx += 192) {
      int r = idx >> 6, kk = idx & 63;
      lds[r * 68 + kk] = A[r * 1024 + kc + kk];
    }
    __syncthreads();
#pragma unroll 2
    for (int k = 0; k < 64; k += 4) {
      const float* Wp = W + (size_t)(kc + k) * NC + c0 + tc * 4;
      float4 w0 = *(const float4*)(Wp);
      float4 w1 = *(const float4*)(Wp + NC);
      float4 w2 = *(const float4*)(Wp + 2 * (size_t)NC);
      float4 w3 = *(const float4*)(Wp + 3 * (size_t)NC);
#pragma unroll
      for (int i = 0; i < 4; i++) {
        const float4 av = *(const float4*)&lds[(tr + 16 * i) * 68 + k];
        acc[i][0] += av.x * w0.x + av.y * w1.x + av.z * w2.x + av.w * w3.x;
        acc[i][1] += av.x * w0.y + av.y * w1.y + av.z * w2.y + av.w * w3.y;
        acc[i][2] += av.x * w0.z + av.y * w1.z + av.z * w2.z + av.w * w3.z;
        acc[i][3] += av.x * w0.w + av.y * w1.w + av.z * w2.w + av.w * w3.w;
      }
    }
  }
  __syncthreads();  // A-stage dead; reuse lds as out tile [node][b][c] padded

#pragma unroll
  for (int j = 0; j < 4; j++) {
    int cl = tc * 4 + j;
    int nl = cl / C, ccl = cl % C;
    float* lp = lds + nl * NODE_P + ccl;
#pragma unroll
    for (int i = 0; i < 4; i++) {
      int b = tr + 16 * i;
      lp[b * C] = tanhf(acc[i][j]);
    }
  }
  __syncthreads();

  // transform (x @ W1) and write bf16, coalesced ushort4
  unsigned short* Hb = Hout + (size_t)c0 * 64;
  for (int f = tid * 4; f < 48 * 64; f += 192 * 4) {
    float vals[4];
#pragma unroll
    for (int e = 0; e < 4; e++) {
      int idx = f + e;
      int n = idx / NODE_F, rem = idx - n * NODE_F;
      int b = rem / C, d = rem - b * C;
      const float* row = lds + n * NODE_P + b * C;
      float v = 0.f;
#pragma unroll
      for (int c = 0; c < C; c++) v += row[c] * w1sh[c * C + d];
      vals[e] = v;
    }
    ushort4 o;
    o.x = f2bf(vals[0]); o.y = f2bf(vals[1]);
    o.z = f2bf(vals[2]); o.w = f2bf(vals[3]);
    *(ushort4*)&Hb[f] = o;
  }
}

__global__ __launch_bounds__(192) void k_gemm_both(const float* __restrict__ net1,
                                                   const float* __restrict__ W_logr,
                                                   const float* __restrict__ W_s,
                                                   const float* __restrict__ W1_logr,
                                                   const float* __restrict__ W1_s,
                                                   unsigned short* __restrict__ hA,
                                                   unsigned short* __restrict__ hB) {
  extern __shared__ float lds[];
  __shared__ float w1sh[36];
  int blk = blockIdx.x;
  if (blk < 1250) gemm_body<6>(net1 + 512, W_s, W1_s, lds, w1sh, hB, 60000, blk);
  else            gemm_body<3>(net1, W_logr, W1_logr, lds, w1sh, hA, 30000, blk - 1250);
}

// ---------------- gathers (CSR by dst), h in bf16 ----------------

template <int C>
__global__ __launch_bounds__(64 * C) void k_gather_out(const unsigned short* __restrict__ h,
    const int* __restrict__ offs, const int* __restrict__ srcn,
    const float* __restrict__ wn, const float* __restrict__ bias,
    float* __restrict__ out, float scale, int outc0) {
  constexpr int BC = 64 * C;
  int n = blockIdx.x, t = threadIdx.x;
  int beg = offs[n], end = offs[n + 1];
  float acc = 0.f;
  int k = beg;
  for (; k + 2 <= end; k += 2) {
    int s0 = srcn[k], s1 = srcn[k + 1];
    float w0 = wn[k], w1 = wn[k + 1];
    acc += w0 * bf2f(h[(size_t)s0 * BC + t]);
    acc += w1 * bf2f(h[(size_t)s1 * BC + t]);
  }
  if (k < end) acc += wn[k] * bf2f(h[(size_t)srcn[k] * BC + t]);
  int b = t / C, c = t - b * C;
  out[(size_t)b * (NNODE * 9) + n * 9 + outc0 + c] = (acc + bias[c]) * scale;
}

// mid gather: tanh(acc + b1), then fused 6x6 W4 transform -> hC (bf16)
__global__ __launch_bounds__(384) void k_gather_mid(const unsigned short* __restrict__ h,
    const int* __restrict__ offs, const int* __restrict__ srcn,
    const float* __restrict__ wn, const float* __restrict__ b1,
    const float* __restrict__ W4, unsigned short* __restrict__ hC) {
  __shared__ float sd[384];
  __shared__ float w4[36];
  int n = blockIdx.x, t = threadIdx.x;
  if (t < 36) w4[t] = W4[t];
  int beg = offs[n], end = offs[n + 1];
  float acc = 0.f;
  int k = beg;
  for (; k + 2 <= end; k += 2) {
    int s0 = srcn[k], s1 = srcn[k + 1];
    float w0 = wn[k], w1 = wn[k + 1];
    acc += w0 * bf2f(h[(size_t)s0 * 384 + t]);
    acc += w1 * bf2f(h[(size_t)s1 * 384 + t]);
  }
  if (k < end) acc += wn[k] * bf2f(h[(size_t)srcn[k] * 384 + t]);
  int b = t / 6, c = t - b * 6;
  sd[t] = tanhf(acc + b1[c]);
  __syncthreads();
  float o = 0.f;
#pragma unroll
  for (int c2 = 0; c2 < 6; c2++) o += sd[b * 6 + c2] * w4[c2 * 6 + c];
  hC[(size_t)n * 384 + t] = f2bf(o);
}

// ---------------- launch ----------------

extern "C" void kernel_launch(void* const* d_in, const int* in_sizes, int n_in,
                              void* d_out, int out_size, void* d_ws, size_t ws_size,
                              hipStream_t stream) {
  const float* net     = (const float*)d_in[0];
  const int*   ei      = (const int*)d_in[1];
  const float* W_mlp2  = (const float*)d_in[2];
  const float* W_logr  = (const float*)d_in[3];
  const float* W_s     = (const float*)d_in[4];
  const float* W1_logr = (const float*)d_in[5];
  const float* b1_logr = (const float*)d_in[6];
  const float* W1_s    = (const float*)d_in[7];
  const float* b1_s    = (const float*)d_in[8];
  const float* W4_s    = (const float*)d_in[9];
  const float* b4_s    = (const float*)d_in[10];
  float* out = (float*)d_out;

  char* w = (char*)d_ws;
  auto carve = [&](size_t nbytes) {
    char* p = w;
    w += (nbytes + 255) & ~(size_t)255;
    return p;
  };
  int*            counts = (int*)           carve(NNODE * 4);
  int*            offs   = (int*)           carve((NNODE + 1) * 4);
  int*            cursor = (int*)           carve(NNODE * 4);
  float*          dinv   = (float*)         carve(NNODE * 4);
  int*            srcn   = (int*)           carve((NEDGE + NNODE) * 4);
  float*          wnorm  = (float*)         carve((NEDGE + NNODE) * 4);
  float*          net1   = (float*)         carve(BATCH * 1024 * 4);
  unsigned short* hA     = (unsigned short*)carve((size_t)NNODE * BATCH * 3 * 2);
  unsigned short* hB     = (unsigned short*)carve((size_t)NNODE * BATCH * 6 * 2);
  unsigned short* hC     = (unsigned short*)carve((size_t)NNODE * BATCH * 6 * 2);

  // graph
  k_init_counts<<<(NNODE + 255) / 256, 256, 0, stream>>>(counts);
  k_count<<<(NEDGE + 255) / 256, 256, 0, stream>>>(ei, counts);
  k_scan<<<1, 1024, 0, stream>>>(counts, offs, cursor, dinv);
  k_fill<<<(NEDGE + NNODE + 255) / 256, 256, 0, stream>>>(ei, dinv, cursor, srcn, wnorm);

  // dense front-end (transforms fused into gemm epilogue)
  k_mlp2<<<256, 256, 0, stream>>>(net, W_mlp2, net1);
  k_gemm_both<<<1875, 192, 17408, stream>>>(net1, W_logr, W_s, W1_logr, W1_s, hA, hB);

  // logr: gather -> out[...,0:3] (*4)
  k_gather_out<3><<<NNODE, 192, 0, stream>>>(hA, offs, srcn, wnorm, b1_logr, out, 4.0f, 0);

  // s: gather+tanh+W4 -> hC; gather -> out[...,3:9] (*50)
  k_gather_mid<<<NNODE, 384, 0, stream>>>(hB, offs, srcn, wnorm, b1_s, W4_s, hC);
  k_gather_out<6><<<NNODE, 384, 0, stream>>>(hC, offs, srcn, wnorm, b4_s, out, 50.0f, 3);
}

// Round 7
// 575.191 us; speedup vs baseline: 1.2400x; 1.2400x over previous
//
#include <hip/hip_runtime.h>
#include <math.h>

#define NNODE 10000
#define NEDGE 160000
#define BATCH 64
#define KDIM  512   // inner dim of the two big GEMMs

// ---- bf16 helpers (RNE) ----
__device__ __forceinline__ unsigned short f2bf(float x) {
  union { float f; unsigned u; } v; v.f = x;
  return (unsigned short)((v.u + 0x7FFF + ((v.u >> 16) & 1)) >> 16);
}
__device__ __forceinline__ float bf2f(unsigned short h) {
  union { unsigned u; float f; } v; v.u = ((unsigned)h) << 16;
  return v.f;
}

// ---------------- graph build ----------------

__global__ void k_init_counts(int* counts) {
  int i = blockIdx.x * 256 + threadIdx.x;
  if (i < NNODE) counts[i] = 1;   // self-loop
}

__global__ void k_count(const int* __restrict__ ei, int* counts) {
  int e = blockIdx.x * 256 + threadIdx.x;
  if (e < NEDGE) atomicAdd(&counts[ei[NEDGE + e]], 1);  // dst row
}

__global__ __launch_bounds__(1024) void k_scan(const int* __restrict__ counts,
                                               int* offs, int* cursor, float* dinv) {
  __shared__ int sd[1024];
  int t = threadIdx.x;
  int b0 = t * 10, b1 = b0 + 10;
  if (b1 > NNODE) b1 = NNODE;
  if (b0 > NNODE) b0 = NNODE;
  int s = 0;
  for (int i = b0; i < b1; i++) s += counts[i];
  sd[t] = s;
  __syncthreads();
  for (int off = 1; off < 1024; off <<= 1) {
    int v = (t >= off) ? sd[t - off] : 0;
    __syncthreads();
    sd[t] += v;
    __syncthreads();
  }
  int excl = (t == 0) ? 0 : sd[t - 1];
  for (int i = b0; i < b1; i++) {
    offs[i] = excl;
    cursor[i] = excl;
    dinv[i] = rsqrtf((float)counts[i]);
    excl += counts[i];
  }
  if (t == 1023) offs[NNODE] = sd[1023];
}

__global__ void k_fill(const int* __restrict__ ei, const float* __restrict__ dinv,
                       int* cursor, int* srcn, float* wnorm) {
  int e = blockIdx.x * 256 + threadIdx.x;
  if (e >= NEDGE + NNODE) return;
  int s, d;
  if (e < NEDGE) { s = ei[e]; d = ei[NEDGE + e]; }
  else           { s = e - NEDGE; d = s; }
  int pos = atomicAdd(&cursor[d], 1);
  srcn[pos] = s;
  wnorm[pos] = dinv[s] * dinv[d];
}

// ---------------- mlp2: net1 = tanh(net @ W_mlp2), [64,640]@[640,1024] ----------------

__global__ __launch_bounds__(256) void k_mlp2(const float* __restrict__ net,
                                              const float* __restrict__ W,
                                              float* __restrict__ net1) {
  __shared__ float a[640];
  int bb = blockIdx.x >> 2, cg = (blockIdx.x & 3) << 8;
  int t = threadIdx.x;
  for (int i = t; i < 640; i += 256) a[i] = net[bb * 640 + i];
  __syncthreads();
  float acc = 0.f;
#pragma unroll 8
  for (int k = 0; k < 640; k++) acc += a[k] * W[k * 1024 + cg + t];
  net1[bb * 1024 + cg + t] = tanhf(acc);
}

// ------------- fused big GEMM + tanh + per-node CxC transform -------------
// H_trans[(n*64+b)*C + d] = sum_c tanh(sum_k A[b,k] W[k,n*C+c]) * W1[c,d]   (bf16 out)
// No LDS staging of A: net1 is 256KB, L1/L2-resident; lanes sharing tr broadcast.
// Tile 64 rows x 96 cols. 192 thr = 12 col-thr (8 cols, 2x float4 W loads) x
// 16 row-thr (4 rows: r = tr+16i). Per 4k-step: 4 A float4 + 8 W float4 -> 128 FMA.
// LDS only for the epilogue transpose/transform tile.

template <int C>
__device__ __forceinline__ void gemm_body(const float* __restrict__ A,
                                          const float* __restrict__ W,
                                          const float* __restrict__ W1,
                                          float* lds, float* w1sh,
                                          unsigned short* __restrict__ Hout,
                                          int NC, int blk) {
  constexpr int NODE_F = 64 * C;        // elems per node chunk
  constexpr int NODE_P = NODE_F + 4;    // padded LDS stride
  int tid = threadIdx.x;
  if (tid < C * C) w1sh[tid] = W1[tid];
  int tc = tid % 12, tr = tid / 12;
  int c0 = blk * 96;
  int cb = min(c0 + tc * 8, NC - 8);    // clamped for the C=3 tail block

  float acc[4][8];
#pragma unroll
  for (int i = 0; i < 4; i++)
#pragma unroll
    for (int j = 0; j < 8; j++) acc[i][j] = 0.f;

#pragma unroll 2
  for (int k = 0; k < KDIM; k += 4) {
    float4 av[4];
#pragma unroll
    for (int i = 0; i < 4; i++)
      av[i] = *(const float4*)&A[(tr + 16 * i) * 1024 + k];
    const float* Wp = W + (size_t)k * NC + cb;
    float4 wv[4][2];
#pragma unroll
    for (int kk = 0; kk < 4; kk++) {
      wv[kk][0] = *(const float4*)(Wp + (size_t)kk * NC);
      wv[kk][1] = *(const float4*)(Wp + (size_t)kk * NC + 4);
    }
#pragma unroll
    for (int i = 0; i < 4; i++) {
#pragma unroll
      for (int jh = 0; jh < 2; jh++) {
        acc[i][jh * 4 + 0] += av[i].x * wv[0][jh].x + av[i].y * wv[1][jh].x +
                              av[i].z * wv[2][jh].x + av[i].w * wv[3][jh].x;
        acc[i][jh * 4 + 1] += av[i].x * wv[0][jh].y + av[i].y * wv[1][jh].y +
                              av[i].z * wv[2][jh].y + av[i].w * wv[3][jh].y;
        acc[i][jh * 4 + 2] += av[i].x * wv[0][jh].z + av[i].y * wv[1][jh].z +
                              av[i].z * wv[2][jh].z + av[i].w * wv[3][jh].z;
        acc[i][jh * 4 + 3] += av[i].x * wv[0][jh].w + av[i].y * wv[1][jh].w +
                              av[i].z * wv[2][jh].w + av[i].w * wv[3][jh].w;
      }
    }
  }

  int nact = min(96, NC - c0);          // active cols this block (multiple of C)
  __syncthreads();                      // w1sh ready; lds free
#pragma unroll
  for (int j = 0; j < 8; j++) {
    int cl = tc * 8 + j;
    if (cl < nact) {
      int nl = cl / C, ccl = cl % C;
      float* lp = lds + nl * NODE_P + ccl;
#pragma unroll
      for (int i = 0; i < 4; i++) {
        int b = tr + 16 * i;
        lp[b * C] = tanhf(acc[i][j]);
      }
    }
  }
  __syncthreads();

  // transform (x @ W1) and write bf16, coalesced ushort4
  int region = nact * 64;
  unsigned short* Hb = Hout + (size_t)c0 * 64;
  for (int f = tid * 4; f < region; f += 192 * 4) {
    float vals[4];
#pragma unroll
    for (int e = 0; e < 4; e++) {
      int idx = f + e;
      int n = idx / NODE_F, rem = idx - n * NODE_F;
      int b = rem / C, d = rem - b * C;
      const float* row = lds + n * NODE_P + b * C;
      float v = 0.f;
#pragma unroll
      for (int c = 0; c < C; c++) v += row[c] * w1sh[c * C + d];
      vals[e] = v;
    }
    ushort4 o;
    o.x = f2bf(vals[0]); o.y = f2bf(vals[1]);
    o.z = f2bf(vals[2]); o.w = f2bf(vals[3]);
    *(ushort4*)&Hb[f] = o;
  }
}

__global__ __launch_bounds__(192) void k_gemm_both(const float* __restrict__ net1,
                                                   const float* __restrict__ W_logr,
                                                   const float* __restrict__ W_s,
                                                   const float* __restrict__ W1_logr,
                                                   const float* __restrict__ W1_s,
                                                   unsigned short* __restrict__ hA,
                                                   unsigned short* __restrict__ hB) {
  extern __shared__ float lds[];
  __shared__ float w1sh[36];
  int blk = blockIdx.x;
  if (blk < 625) gemm_body<6>(net1 + 512, W_s, W1_s, lds, w1sh, hB, 60000, blk);
  else           gemm_body<3>(net1, W_logr, W1_logr, lds, w1sh, hA, 30000, blk - 625);
}

// ---------------- gathers (CSR by dst), h in bf16 ----------------
// XCD-chunked node swizzle: consecutive blocks on one XCD get consecutive nodes
// (L2 write-combining on out lines + h-read locality). 10000 = 8 * 1250 exact.
__device__ __forceinline__ int swz_node(int blk) {
  return (blk & 7) * 1250 + (blk >> 3);
}

// mid gather: tanh(acc + b1), then fused 6x6 W4 transform -> hC (bf16)
__global__ __launch_bounds__(384) void k_gather_mid(const unsigned short* __restrict__ h,
    const int* __restrict__ offs, const int* __restrict__ srcn,
    const float* __restrict__ wn, const float* __restrict__ b1,
    const float* __restrict__ W4, unsigned short* __restrict__ hC) {
  __shared__ float sd[384];
  __shared__ float w4[36];
  int n = swz_node(blockIdx.x), t = threadIdx.x;
  if (t < 36) w4[t] = W4[t];
  int beg = offs[n], end = offs[n + 1];
  float acc = 0.f;
  int k = beg;
  for (; k + 4 <= end; k += 4) {
    int s0 = srcn[k], s1 = srcn[k + 1], s2 = srcn[k + 2], s3 = srcn[k + 3];
    float w0 = wn[k], w1 = wn[k + 1], w2 = wn[k + 2], w3 = wn[k + 3];
    float h0 = bf2f(h[(size_t)s0 * 384 + t]);
    float h1 = bf2f(h[(size_t)s1 * 384 + t]);
    float h2 = bf2f(h[(size_t)s2 * 384 + t]);
    float h3 = bf2f(h[(size_t)s3 * 384 + t]);
    acc += w0 * h0 + w1 * h1 + w2 * h2 + w3 * h3;
  }
  for (; k < end; k++) acc += wn[k] * bf2f(h[(size_t)srcn[k] * 384 + t]);
  int b = t / 6, c = t - b * 6;
  sd[t] = tanhf(acc + b1[c]);
  __syncthreads();
  float o = 0.f;
#pragma unroll
  for (int c2 = 0; c2 < 6; c2++) o += sd[b * 6 + c2] * w4[c2 * 6 + c];
  hC[(size_t)n * 384 + t] = f2bf(o);
}

// final merged gather: all 9 output channels in one block -> full 36B out rows
__global__ __launch_bounds__(576) void k_gather_out9(
    const unsigned short* __restrict__ hA, const unsigned short* __restrict__ hC,
    const int* __restrict__ offs, const int* __restrict__ srcn,
    const float* __restrict__ wn, const float* __restrict__ b_logr,
    const float* __restrict__ b_s, float* __restrict__ out) {
  int n = swz_node(blockIdx.x), t = threadIdx.x;
  int b = t / 9, c = t - b * 9;
  bool isl = (c < 3);
  const unsigned short* h = isl ? hA : hC;
  int stride = isl ? 192 : 384;
  int off = isl ? (b * 3 + c) : (b * 6 + (c - 3));
  int beg = offs[n], end = offs[n + 1];
  float acc = 0.f;
  int k = beg;
  for (; k + 4 <= end; k += 4) {
    int s0 = srcn[k], s1 = srcn[k + 1], s2 = srcn[k + 2], s3 = srcn[k + 3];
    float w0 = wn[k], w1 = wn[k + 1], w2 = wn[k + 2], w3 = wn[k + 3];
    float h0 = bf2f(h[(size_t)s0 * stride + off]);
    float h1 = bf2f(h[(size_t)s1 * stride + off]);
    float h2 = bf2f(h[(size_t)s2 * stride + off]);
    float h3 = bf2f(h[(size_t)s3 * stride + off]);
    acc += w0 * h0 + w1 * h1 + w2 * h2 + w3 * h3;
  }
  for (; k < end; k++) acc += wn[k] * bf2f(h[(size_t)srcn[k] * stride + off]);
  float bias = isl ? b_logr[c] : b_s[c - 3];
  float scale = isl ? 4.0f : 50.0f;
  out[(size_t)b * (NNODE * 9) + n * 9 + c] = (acc + bias) * scale;
}

// ---------------- launch ----------------

extern "C" void kernel_launch(void* const* d_in, const int* in_sizes, int n_in,
                              void* d_out, int out_size, void* d_ws, size_t ws_size,
                              hipStream_t stream) {
  const float* net     = (const float*)d_in[0];
  const int*   ei      = (const int*)d_in[1];
  const float* W_mlp2  = (const float*)d_in[2];
  const float* W_logr  = (const float*)d_in[3];
  const float* W_s     = (const float*)d_in[4];
  const float* W1_logr = (const float*)d_in[5];
  const float* b1_logr = (const float*)d_in[6];
  const float* W1_s    = (const float*)d_in[7];
  const float* b1_s    = (const float*)d_in[8];
  const float* W4_s    = (const float*)d_in[9];
  const float* b4_s    = (const float*)d_in[10];
  float* out = (float*)d_out;

  char* w = (char*)d_ws;
  auto carve = [&](size_t nbytes) {
    char* p = w;
    w += (nbytes + 255) & ~(size_t)255;
    return p;
  };
  int*            counts = (int*)           carve(NNODE * 4);
  int*            offs   = (int*)           carve((NNODE + 1) * 4);
  int*            cursor = (int*)           carve(NNODE * 4);
  float*          dinv   = (float*)         carve(NNODE * 4);
  int*            srcn   = (int*)           carve((NEDGE + NNODE) * 4);
  float*          wnorm  = (float*)         carve((NEDGE + NNODE) * 4);
  float*          net1   = (float*)         carve(BATCH * 1024 * 4);
  unsigned short* hA     = (unsigned short*)carve((size_t)NNODE * BATCH * 3 * 2);
  unsigned short* hB     = (unsigned short*)carve((size_t)NNODE * BATCH * 6 * 2);
  unsigned short* hC     = (unsigned short*)carve((size_t)NNODE * BATCH * 6 * 2);

  // graph
  k_init_counts<<<(NNODE + 255) / 256, 256, 0, stream>>>(counts);
  k_count<<<(NEDGE + 255) / 256, 256, 0, stream>>>(ei, counts);
  k_scan<<<1, 1024, 0, stream>>>(counts, offs, cursor, dinv);
  k_fill<<<(NEDGE + NNODE + 255) / 256, 256, 0, stream>>>(ei, dinv, cursor, srcn, wnorm);

  // dense front-end (transforms fused into gemm epilogue)
  k_mlp2<<<256, 256, 0, stream>>>(net, W_mlp2, net1);
  k_gemm_both<<<938, 192, 25088, stream>>>(net1, W_logr, W_s, W1_logr, W1_s, hA, hB);

  // s: gather+tanh+W4 -> hC
  k_gather_mid<<<NNODE, 384, 0, stream>>>(hB, offs, srcn, wnorm, b1_s, W4_s, hC);

  // merged final gather: logr (*4, ch 0-2) + s (*50, ch 3-8)
  k_gather_out9<<<NNODE, 576, 0, stream>>>(hA, hC, offs, srcn, wnorm, b1_logr, b4_s, out);
}